// Round 1
// 208.499 us; speedup vs baseline: 1.1090x; 1.1090x over previous
//
#include <hip/hip_runtime.h>

// GPConv1d: out[b,o,kb,w] = sum_{i,j,c,v} G[i,j,kb] W[v,c,o,i] xpad[b,c,j,w+v] + bias[o,kb]
// GEMM view: out[ok][b,w] = sum_kd kern[ok][kd] X[kd][b,w], M=512, N=32768, K=2560
// Pipeline restructure (T3+T4+T5+T14):
//   - As double-buffered over v; glds(v+1) issued before compute(v); raw s_barrier
//     with COUNTED s_waitcnt vmcnt(N) (never 0 in steady state) so prefetch stays
//     in flight across barriers.
//   - kern tiles stored XOR-swizzled (row r: elem col ^= (r&7)<<3) with NO pad ->
//     tile = 128x64 = exactly 1024 16B chunks = 4 glds/thread/wave (uniform vmcnt).
//     Read-side swizzle keeps A-frag ds_read_b128 at 2-way bank aliasing (free).
//   - x window loads for cjb+1 issued at v=3 (exactly 40 vmem instrs per wave,
//     tail items spread over all waves), cvt+ds_write after cjb-end barrier (T14).
//   - s_setprio(1) around MFMA clusters (T5).

#define C_    64
#define L_    4096
#define PAD_  2
#define OKch  512
#define KD_   2560

#define BM    128
#define BN    128
#define BKCJ  64        // cj per block-tile
#define NCJB  8         // 512/64
#define NV    5
#define TILE  8192      // kern tile: 128 rows x 64 elems (16 KB), XOR-swizzled
#define ASTR  72        // Bs row stride (elems): 64 + 8 pad (2-way reads)
#define WIN   132       // Bs rows: w0-2 .. w0+129

typedef __bf16 bf16x8 __attribute__((ext_vector_type(8)));
typedef float floatx4 __attribute__((ext_vector_type(4)));

__device__ __forceinline__ unsigned short f2bf(float f) {
    unsigned int u = __float_as_uint(f);
    u += 0x7FFFu + ((u >> 16) & 1u);
    return (unsigned short)(u >> 16);
}

__device__ __forceinline__ void glds16(const unsigned short* g, unsigned short* l) {
    __builtin_amdgcn_global_load_lds(
        (const __attribute__((address_space(1))) unsigned int*)(g),
        (__attribute__((address_space(3))) unsigned int*)(l),
        16, 0, 0);
}

#define WAIT_VMCNT_0()  asm volatile("s_waitcnt vmcnt(0)" ::: "memory")
#define WAIT_VMCNT_4()  asm volatile("s_waitcnt vmcnt(4)" ::: "memory")
#define WAIT_VMCNT_44() asm volatile("s_waitcnt vmcnt(44)" ::: "memory")
#define WAIT_LGKM_0()   asm volatile("s_waitcnt lgkmcnt(0)" ::: "memory")

__device__ __forceinline__ void barrier_raw() {
    asm volatile("" ::: "memory");
    __builtin_amdgcn_sched_barrier(0);
    __builtin_amdgcn_s_barrier();
    __builtin_amdgcn_sched_barrier(0);
    asm volatile("" ::: "memory");
}

// ---- kernel 1: build kern, XOR-swizzled tiles for uniform glds staging.
// kern value for (ok, kd=(v,cj)) = sum_i G[i,j,kb] W[v,c,o,i], cj=c*8+j, ok=o*8+kb
// tile ((y*8+cjb)*5+v), elem m*64 + (kk ^ ((m&7)<<3)),  y=ok>>7, m=ok&127, kk=cj&63
__global__ __launch_bounds__(256) void build_kern(
    const float* __restrict__ W, const float* __restrict__ G,
    unsigned short* __restrict__ kernT)
{
    const int ok = blockIdx.y;                     // 0..511
    const int kd = blockIdx.x * 256 + threadIdx.x; // 0..2559
    const int v  = kd >> 9;
    const int cj = kd & 511;
    const int c  = cj >> 3;
    const int j  = cj & 7;
    const int o  = ok >> 3;
    const int kb = ok & 7;
    const float* Wp = W + (((v * C_ + c) * 64 + o) << 3);  // 8 i-contiguous floats
    const float4 w0 = *(const float4*)Wp;
    const float4 w1 = *(const float4*)(Wp + 4);
    const int gb = j * 8 + kb;                     // G[i][j][kb], i stride 64
    float s = G[gb]       * w0.x + G[gb + 64]  * w0.y
            + G[gb + 128] * w0.z + G[gb + 192] * w0.w
            + G[gb + 256] * w1.x + G[gb + 320] * w1.y
            + G[gb + 384] * w1.z + G[gb + 448] * w1.w;
    const int y   = ok >> 7;
    const int m   = ok & 127;
    const int cjb = cj >> 6;
    const int kk  = cj & 63;
    kernT[(size_t)(((y * NCJB + cjb) * NV + v)) * TILE
          + m * 64 + (kk ^ ((m & 7) << 3))] = f2bf(s);
}

// ---- x-window prefetch: exactly 40 vmem instrs per wave (32 full + 8 tail).
// item idx -> (kgrp=idx/132, nn=idx%132); loads clamped (OOB zeroed at store).
__device__ __forceinline__ void b_issue(const float* xb, int cj0, int w0,
                                        float br[5][8]) {
    const int tid = threadIdx.x;
    #pragma unroll
    for (int u = 0; u < 5; u++) {
        int idx; bool act;
        if (u < 4) { idx = u * 256 + tid; act = true; }
        else { act = ((tid & 7) == 0);
               idx = 1024 + ((tid >> 6) << 3) + ((tid >> 3) & 7); }
        if (act) {
            const int kgrp = idx / WIN;
            const int nn   = idx - kgrp * WIN;
            int ws = w0 - PAD_ + nn;
            ws = ws < 0 ? 0 : (ws > (L_ - 1) ? (L_ - 1) : ws);
            const float* xp = xb + ((size_t)(cj0 + (kgrp << 3)) << 12) + (size_t)ws;
            #pragma unroll
            for (int r = 0; r < 8; r++)
                br[u][r] = xp[(size_t)r << 12];
        }
    }
}

__device__ __forceinline__ void b_store(unsigned short* BsP, const float br[5][8],
                                        int w0) {
    const int tid = threadIdx.x;
    #pragma unroll
    for (int u = 0; u < 5; u++) {
        int idx; bool act;
        if (u < 4) { idx = u * 256 + tid; act = true; }
        else { act = ((tid & 7) == 0);
               idx = 1024 + ((tid >> 6) << 3) + ((tid >> 3) & 7); }
        if (act) {
            const int kgrp = idx / WIN;
            const int nn   = idx - kgrp * WIN;
            const bool inb = (unsigned)(w0 - PAD_ + nn) < (unsigned)L_;
            unsigned int pk[4];
            #pragma unroll
            for (int r = 0; r < 8; r++) {
                const unsigned short h = f2bf(inb ? br[u][r] : 0.0f);
                if (r & 1) pk[r >> 1] |= (unsigned int)h << 16;
                else       pk[r >> 1]  = h;
            }
            uint4 uu; uu.x = pk[0]; uu.y = pk[1]; uu.z = pk[2]; uu.w = pk[3];
            *reinterpret_cast<uint4*>(&BsP[nn * ASTR + (kgrp << 3)]) = uu;
        }
    }
}

// ---- A-tile stage: exactly 4 glds per thread (1024 x 16B chunks), linear copy
// (swizzle already baked into the tile by build_kern).
__device__ __forceinline__ void a_stage(const unsigned short* tile,
                                        unsigned short* dst) {
    const int tid = threadIdx.x;
    #pragma unroll
    for (int u = 0; u < 4; u++) {
        const int e = (u * 256 + tid) << 3;
        glds16(tile + e, dst + e);
    }
}

// ---- kernel 2: MFMA GEMM, 128x128 C-tile, counted-vmcnt pipeline.
__global__ __launch_bounds__(256, 2) void gpconv_mfma(
    const float* __restrict__ x, const unsigned short* __restrict__ kernT,
    const float* __restrict__ bias, float* __restrict__ out)
{
    __shared__ unsigned short As[2 * TILE];   // 32768 B (double-buffered kern tile)
    __shared__ unsigned short Bs[WIN * ASTR]; // 19008 B (x window)

    const int tid  = threadIdx.x;
    const int lane = tid & 63;
    const int wave = tid >> 6;
    const int lrow = lane & 15;
    const int quad = lane >> 4;
    const int wm = (wave >> 1) << 6;   // 2x2 wave grid, 64x64 each
    const int wn = (wave & 1) << 6;

    // XCD-aware remap: 4 y-blocks sharing an x-window land on the same XCD
    const int bid = blockIdx.x;              // 0..1023
    const int y   = (bid >> 3) & 3;
    const int xw  = ((bid >> 5) << 3) + (bid & 7);  // 0..255
    const int b   = xw >> 5;
    const int w0  = (xw & 31) * BN;
    const int mBase = y * BM;
    const float* xb = x + (size_t)b * (size_t)(512 * L_);
    const unsigned short* ky = kernT + (size_t)(y * NCJB) * NV * TILE;

    // A-frag addressing: row = wm + mt*16 + lrow; swizzle = ((row&7)<<3) = lane-const
    const int asw   = (lrow & 7) << 3;
    const int c0    = (quad << 3) ^ asw;          // kk2=0 elem col
    const int c1    = (32 + (quad << 3)) ^ asw;   // kk2=1 elem col
    const int arow0 = (wm + lrow) << 6;

    floatx4 acc[4][4];
    {
        const floatx4 z = {0.f, 0.f, 0.f, 0.f};
        #pragma unroll
        for (int i2 = 0; i2 < 4; i2++)
            #pragma unroll
            for (int j2 = 0; j2 < 4; j2++) acc[i2][j2] = z;
    }

    float br[5][8];

    // ---- prologue: window(cjb=0) + tile(0,0); full drain once.
    b_issue(xb, 0, w0, br);                 // queue: [B(40)]
    a_stage(ky, As);                        // queue: [B(40), G0(4)]
    WAIT_VMCNT_4();                         // B done, G0 may fly
    b_store(Bs, br, w0);
    __syncthreads();                        // drains vmcnt+lgkm; As[0]+Bs ready

    for (int cjb = 0; cjb < NCJB; cjb++) {
        const unsigned short* tcjb = ky + (size_t)cjb * NV * TILE;
        const bool last = (cjb == NCJB - 1);
        #pragma unroll
        for (int v = 0; v < NV; v++) {
            const int pv = (cjb & 1) ^ (v & 1);   // As parity holding tile v
            // bar1: all waves done reading As[pv^1] (previous phase)
            WAIT_LGKM_0();
            barrier_raw();
            // issue next A tile into the buffer just freed
            if (v < 4)       a_stage(tcjb + (size_t)(v + 1) * TILE, &As[(pv ^ 1) * TILE]);
            else if (!last)  a_stage(tcjb + (size_t)NV * TILE,      &As[(pv ^ 1) * TILE]);
            // issue next x window 2 phases ahead of use
            if (v == 3 && !last) b_issue(xb, (cjb + 1) * BKCJ, w0, br);
            // counted wait for THIS phase's tile (ledger per wave):
            //  v0..v2: [Gv, Gv+1] -> 4 ;  v3: [G3,G4,B40] -> 44 (G3 done)
            //  v4(!last): [G4,B40,G0'] -> 44 (G4 done) ; v4(last): [G4] -> 0
            if ((v == 3 || v == 4) && !last) { WAIT_VMCNT_44(); }
            else if (v == 4 && last)         { WAIT_VMCNT_0();  }
            else                             { WAIT_VMCNT_4();  }
            barrier_raw();   // bar2: tile visible to all waves
            // ---- compute v: per 32-wide k-chunk, 8 frag reads + 16 MFMA
            const unsigned short* Ab = &As[pv * TILE];
            #pragma unroll
            for (int kk2 = 0; kk2 < 2; kk2++) {
                const int cc = kk2 ? c1 : c0;
                bf16x8 af[4], bfr[4];
                #pragma unroll
                for (int mt = 0; mt < 4; mt++)
                    af[mt] = *reinterpret_cast<const bf16x8*>(
                        &Ab[arow0 + (mt << 10) + cc]);
                #pragma unroll
                for (int nt = 0; nt < 4; nt++)
                    bfr[nt] = *reinterpret_cast<const bf16x8*>(
                        &Bs[(wn + (nt << 4) + lrow + v) * ASTR + (kk2 << 5) + (quad << 3)]);
                __builtin_amdgcn_s_setprio(1);
                #pragma unroll
                for (int mt = 0; mt < 4; mt++)
                    #pragma unroll
                    for (int nt = 0; nt < 4; nt++)
                        acc[mt][nt] = __builtin_amdgcn_mfma_f32_16x16x32_bf16(
                            af[mt], bfr[nt], acc[mt][nt], 0, 0, 0);
                __builtin_amdgcn_s_setprio(0);
            }
        }
        // ---- cjb end: rewrite Bs with next window (B regs loaded at v=3)
        if (!last) {
            WAIT_LGKM_0();
            barrier_raw();          // all waves done v4 reads of Bs
            WAIT_VMCNT_4();         // B(40) landed; G0' stays in flight
            b_store(Bs, br, w0);
            WAIT_LGKM_0();          // writes committed before next bar1
        }
    }

    // ---- epilogue: C/D layout col(n)=lane&15, row(m)=quad*4+e
    #pragma unroll
    for (int mt = 0; mt < 4; mt++) {
        #pragma unroll
        for (int e = 0; e < 4; e++) {
            const int okc = mBase + wm + (mt << 4) + (quad << 2) + e;
            const float bv = bias[okc];
            float* orow = out + ((size_t)b * OKch + (size_t)okc) * L_ + w0;
            #pragma unroll
            for (int nt = 0; nt < 4; nt++) {
                const int n = wn + (nt << 4) + lrow;
                orow[n] = acc[mt][nt][e] + bv;
            }
        }
    }
}

extern "C" void kernel_launch(void* const* d_in, const int* in_sizes, int n_in,
                              void* d_out, int out_size, void* d_ws, size_t ws_size,
                              hipStream_t stream) {
    const float* x    = (const float*)d_in[0];  // (8,64,8,4096)
    const float* W    = (const float*)d_in[1];  // (5,64,64,8)
    const float* bias = (const float*)d_in[2];  // (1,64,8,1) -> [512]
    const float* G    = (const float*)d_in[3];  // (8,8,8)
    unsigned short* kernT = (unsigned short*)d_ws;  // 160 tiles x 16384 B = 2.62 MB
    float* out = (float*)d_out;

    build_kern<<<dim3(KD_ / 256, OKch), 256, 0, stream>>>(W, G, kernT);
    gpconv_mfma<<<dim3(1024), 256, 0, stream>>>(x, kernT, bias, out);
}

// Round 2
// 184.943 us; speedup vs baseline: 1.2503x; 1.1274x over previous
//
#include <hip/hip_runtime.h>

// GPConv1d: out[b,o,kb,w] = sum_{i,j,c,v} G[i,j,kb] W[v,c,o,i] xpad[b,c,j,w+v] + bias[o,kb]
// GEMM view: out[ok][b,w] = sum_kd kern[ok][kd] X[kd][b,w], M=512, N=32768, K=2560
// R2 restructure: A (kern, 2.6 MB, L2-resident) no longer staged through LDS.
//   - build_kern emits fragment-coalesced tiles: frag (mq,kk2,quad,lrow,e) at
//     ((mq*2+kk2)*4+quad)*128 + lrow*8 + e -> each wave's frag load is a
//     contiguous 1KB global_load_dwordx4 (lane l reads 16B at base+l*16).
//   - A-frags double-buffered in REGISTERS (aX/aY, 8 frags each), prefetch
//     distance 1 phase, compiler-managed vmcnt (plain VGPR loads).
//   - LDS holds only the x window Bs (19 KB). Barriers: 2 per cjb (16 total,
//     raw s_barrier + lgkmcnt only -- in-flight global loads cross freely).
//   - T14 split for Bs kept: b_issue at v=3, b_store after cjb-end barrier.
//   - T5 setprio around MFMA cluster kept.

#define C_    64
#define L_    4096
#define PAD_  2
#define OKch  512
#define KD_   2560

#define BM    128
#define BN    128
#define BKCJ  64        // cj per block-tile
#define NCJB  8         // 512/64
#define NV    5
#define TILE  8192      // kern tile: 128 rows x 64 cols (16 KB), frag-coalesced
#define ASTR  72        // Bs row stride (elems): 64 + 8 pad (2-way reads = free)
#define WIN   132       // Bs rows: w0-2 .. w0+129

typedef __bf16 bf16x8 __attribute__((ext_vector_type(8)));
typedef float floatx4 __attribute__((ext_vector_type(4)));

__device__ __forceinline__ unsigned short f2bf(float f) {
    unsigned int u = __float_as_uint(f);
    u += 0x7FFFu + ((u >> 16) & 1u);
    return (unsigned short)(u >> 16);
}

#define WAIT_LGKM_0() asm volatile("s_waitcnt lgkmcnt(0)" ::: "memory")

__device__ __forceinline__ void barrier_raw() {
    asm volatile("" ::: "memory");
    __builtin_amdgcn_sched_barrier(0);
    __builtin_amdgcn_s_barrier();
    __builtin_amdgcn_sched_barrier(0);
    asm volatile("" ::: "memory");
}

// ---- kernel 1: build kern in fragment-coalesced tile layout, 8 outputs/thread.
// kern value (ok, kd=(v,cj)) = sum_i G[i,j,kb] W[v,c,o,i], cj=c*8+j, ok=o*8+kb.
// For fixed (ok,v,c), j=0..7 are the 8 contiguous elems of one 16B store:
// tile t=(y*8+cjb)*5+v, offset f*512 + quad*128 + lrow*8 + j,
//   f=(m>>4)*2+((c>>2)&1), quad=c&3, lrow=m&15.
__global__ __launch_bounds__(256) void build_kern(
    const float* __restrict__ W, const float* __restrict__ G,
    unsigned short* __restrict__ kernT)
{
    const int idx  = blockIdx.x * 256 + threadIdx.x;  // 0..163839
    const int lrow = idx & 15;
    const int quad = (idx >> 4) & 3;
    const int f    = (idx >> 6) & 15;
    const int mq   = f >> 1;
    const int kk2  = f & 1;
    const int t    = idx >> 10;          // (y*8+cjb)*5+v, 0..159
    const int v    = t % 5;
    const int tc   = t / 5;
    const int cjb  = tc & 7;
    const int y    = tc >> 3;
    const int m    = (mq << 4) | lrow;
    const int ok   = (y << 7) | m;
    const int o    = ok >> 3;
    const int kb   = ok & 7;
    const int c    = (cjb << 3) | (kk2 << 2) | quad;

    const float* Wp = W + (((v * C_ + c) * 64 + o) << 3);  // 8 i-contiguous
    const float4 w0 = *(const float4*)Wp;
    const float4 w1 = *(const float4*)(Wp + 4);
    const float w[8] = {w0.x, w0.y, w0.z, w0.w, w1.x, w1.y, w1.z, w1.w};

    unsigned int pk[4];
    #pragma unroll
    for (int j = 0; j < 8; j++) {
        float s = 0.f;
        #pragma unroll
        for (int i = 0; i < 8; i++)
            s += G[i * 64 + j * 8 + kb] * w[i];
        const unsigned short h = f2bf(s);
        if (j & 1) pk[j >> 1] |= (unsigned int)h << 16;
        else       pk[j >> 1]  = h;
    }
    uint4 uu; uu.x = pk[0]; uu.y = pk[1]; uu.z = pk[2]; uu.w = pk[3];
    *reinterpret_cast<uint4*>(
        &kernT[((size_t)t << 13) + (f << 9) + (quad << 7) + (lrow << 3)]) = uu;
}

// ---- x-window prefetch: 40 vmem instrs per wave (32 full + 8 tail items).
__device__ __forceinline__ void b_issue(const float* xb, int cj0, int w0,
                                        float br[5][8]) {
    const int tid = threadIdx.x;
    #pragma unroll
    for (int u = 0; u < 5; u++) {
        int idx; bool act;
        if (u < 4) { idx = u * 256 + tid; act = true; }
        else { act = ((tid & 7) == 0);
               idx = 1024 + ((tid >> 6) << 3) + ((tid >> 3) & 7); }
        if (act) {
            const int kgrp = idx / WIN;
            const int nn   = idx - kgrp * WIN;
            int ws = w0 - PAD_ + nn;
            ws = ws < 0 ? 0 : (ws > (L_ - 1) ? (L_ - 1) : ws);
            const float* xp = xb + ((size_t)(cj0 + (kgrp << 3)) << 12) + (size_t)ws;
            #pragma unroll
            for (int r = 0; r < 8; r++)
                br[u][r] = xp[(size_t)r << 12];
        }
    }
}

__device__ __forceinline__ void b_store(unsigned short* BsP, const float br[5][8],
                                        int w0) {
    const int tid = threadIdx.x;
    #pragma unroll
    for (int u = 0; u < 5; u++) {
        int idx; bool act;
        if (u < 4) { idx = u * 256 + tid; act = true; }
        else { act = ((tid & 7) == 0);
               idx = 1024 + ((tid >> 6) << 3) + ((tid >> 3) & 7); }
        if (act) {
            const int kgrp = idx / WIN;
            const int nn   = idx - kgrp * WIN;
            const bool inb = (unsigned)(w0 - PAD_ + nn) < (unsigned)L_;
            unsigned int pk[4];
            #pragma unroll
            for (int r = 0; r < 8; r++) {
                const unsigned short h = f2bf(inb ? br[u][r] : 0.0f);
                if (r & 1) pk[r >> 1] |= (unsigned int)h << 16;
                else       pk[r >> 1]  = h;
            }
            uint4 uu; uu.x = pk[0]; uu.y = pk[1]; uu.z = pk[2]; uu.w = pk[3];
            *reinterpret_cast<uint4*>(&BsP[nn * ASTR + (kgrp << 3)]) = uu;
        }
    }
}

// ---- A-frag load: 8 contiguous-coalesced 16B loads into regs.
__device__ __forceinline__ void a_load(const unsigned short* t, int wb,
                                       bf16x8 r[8]) {
    #pragma unroll
    for (int f = 0; f < 8; f++)
        r[f] = *reinterpret_cast<const bf16x8*>(t + (f << 9) + wb);
}

__device__ __forceinline__ void compute_phase(
    const bf16x8 a[8], const unsigned short* BsP,
    int wn, int lrow, int quad, int v, floatx4 acc[4][4])
{
    #pragma unroll
    for (int kk2 = 0; kk2 < 2; kk2++) {
        bf16x8 bfr[4];
        #pragma unroll
        for (int nt = 0; nt < 4; nt++)
            bfr[nt] = *reinterpret_cast<const bf16x8*>(
                &BsP[(wn + (nt << 4) + lrow + v) * ASTR + (kk2 << 5) + (quad << 3)]);
        __builtin_amdgcn_s_setprio(1);
        #pragma unroll
        for (int mt = 0; mt < 4; mt++)
            #pragma unroll
            for (int nt = 0; nt < 4; nt++)
                acc[mt][nt] = __builtin_amdgcn_mfma_f32_16x16x32_bf16(
                    a[mt * 2 + kk2], bfr[nt], acc[mt][nt], 0, 0, 0);
        __builtin_amdgcn_s_setprio(0);
    }
}

// ---- kernel 2: MFMA GEMM, 128x128 C-tile, A from L2 via reg double-buffer.
__global__ __launch_bounds__(256, 2) void gpconv_mfma(
    const float* __restrict__ x, const unsigned short* __restrict__ kernT,
    const float* __restrict__ bias, float* __restrict__ out)
{
    __shared__ unsigned short Bs[WIN * ASTR];  // 19008 B, single x window

    const int tid  = threadIdx.x;
    const int lane = tid & 63;
    const int wave = tid >> 6;
    const int lrow = lane & 15;
    const int quad = lane >> 4;
    const int wm = (wave >> 1) << 6;   // 2x2 wave grid, 64x64 each
    const int wn = (wave & 1) << 6;

    // XCD-aware remap: 4 y-blocks sharing an x-window land on the same XCD
    const int bid = blockIdx.x;              // 0..1023
    const int y   = (bid >> 3) & 3;
    const int xw  = ((bid >> 5) << 3) + (bid & 7);  // 0..255
    const int b   = xw >> 5;
    const int w0  = (xw & 31) * BN;
    const int mBase = y * BM;
    const float* xb = x + (size_t)b * (size_t)(512 * L_);
    const unsigned short* ky = kernT + (size_t)(y * NCJB) * NV * TILE;

    // per-lane offset within a frag-coalesced tile: wave's m-range + lane slot
    const int wb = wm * 64 + lane * 8;   // elems

    floatx4 acc[4][4];
    {
        const floatx4 z = {0.f, 0.f, 0.f, 0.f};
        #pragma unroll
        for (int i2 = 0; i2 < 4; i2++)
            #pragma unroll
            for (int j2 = 0; j2 < 4; j2++) acc[i2][j2] = z;
    }

    bf16x8 aX[8], aY[8];
    float br[5][8];

    // ---- prologue: window(cjb=0) + tile p=0 into aX
    b_issue(xb, 0, w0, br);            // queue: [B(40)]
    a_load(ky, wb, aX);                // queue: [B(40), A0(8)]
    b_store(Bs, br, w0);               // compiler waits br (vmcnt(8)); A0 flies
    WAIT_LGKM_0();
    barrier_raw();                     // Bs visible; no vmcnt drain

// phase p = cjb*5+v: compute with CUR (holds tile p), prefetch tile p+1 -> NXT
#define PHASE(CUR, NXT, CJB, V, DO_PRE, DO_BI, DO_ST)                        \
    {                                                                        \
        if (DO_PRE) a_load(ky + (size_t)((CJB) * 5 + (V) + 1) * TILE, wb, NXT); \
        if (DO_BI)  b_issue(xb, ((CJB) + 1) * BKCJ, w0, br);                 \
        compute_phase(CUR, Bs, wn, lrow, quad, (V), acc);                    \
        if (DO_ST) {                                                         \
            barrier_raw();             /* all waves done v=4 Bs reads */     \
            b_store(Bs, br, w0);       /* waits br vmcnt; A-prefetch flies */\
            WAIT_LGKM_0();                                                   \
            barrier_raw();             /* new window visible */              \
        }                                                                    \
    }

    for (int cp = 0; cp < 3; cp++) {   // cjb pairs (0,1),(2,3),(4,5)
        const int c0 = cp * 2, c1 = c0 + 1;
        PHASE(aX, aY, c0, 0, 1, 0, 0);
        PHASE(aY, aX, c0, 1, 1, 0, 0);
        PHASE(aX, aY, c0, 2, 1, 0, 0);
        PHASE(aY, aX, c0, 3, 1, 1, 0);
        PHASE(aX, aY, c0, 4, 1, 0, 1);
        PHASE(aY, aX, c1, 0, 1, 0, 0);
        PHASE(aX, aY, c1, 1, 1, 0, 0);
        PHASE(aY, aX, c1, 2, 1, 0, 0);
        PHASE(aX, aY, c1, 3, 1, 1, 0);
        PHASE(aY, aX, c1, 4, 1, 0, 1);
    }
    // tail: cjb 6,7
    PHASE(aX, aY, 6, 0, 1, 0, 0);
    PHASE(aY, aX, 6, 1, 1, 0, 0);
    PHASE(aX, aY, 6, 2, 1, 0, 0);
    PHASE(aY, aX, 6, 3, 1, 1, 0);
    PHASE(aX, aY, 6, 4, 1, 0, 1);
    PHASE(aY, aX, 7, 0, 1, 0, 0);
    PHASE(aX, aY, 7, 1, 1, 0, 0);
    PHASE(aY, aX, 7, 2, 1, 0, 0);
    PHASE(aX, aY, 7, 3, 1, 0, 0);   // prefetch p=39 only; no next window
    PHASE(aY, aX, 7, 4, 0, 0, 0);   // last phase
#undef PHASE

    // ---- epilogue: C/D layout col(n)=lane&15, row(m)=quad*4+e
    #pragma unroll
    for (int mt = 0; mt < 4; mt++) {
        #pragma unroll
        for (int e = 0; e < 4; e++) {
            const int okc = mBase + wm + (mt << 4) + (quad << 2) + e;
            const float bv = bias[okc];
            float* orow = out + ((size_t)b * OKch + (size_t)okc) * L_ + w0;
            #pragma unroll
            for (int nt = 0; nt < 4; nt++) {
                const int n = wn + (nt << 4) + lrow;
                orow[n] = acc[mt][nt][e] + bv;
            }
        }
    }
}

extern "C" void kernel_launch(void* const* d_in, const int* in_sizes, int n_in,
                              void* d_out, int out_size, void* d_ws, size_t ws_size,
                              hipStream_t stream) {
    const float* x    = (const float*)d_in[0];  // (8,64,8,4096)
    const float* W    = (const float*)d_in[1];  // (5,64,64,8)
    const float* bias = (const float*)d_in[2];  // (1,64,8,1) -> [512]
    const float* G    = (const float*)d_in[3];  // (8,8,8)
    unsigned short* kernT = (unsigned short*)d_ws;  // 160 tiles x 16384 B = 2.62 MB
    float* out = (float*)d_out;

    build_kern<<<dim3(640), 256, 0, stream>>>(W, G, kernT);
    gpconv_mfma<<<dim3(1024), 256, 0, stream>>>(x, kernT, bias, out);
}